// Round 6
// baseline (60.339 us; speedup 1.0000x reference)
//
#include <hip/hip_runtime.h>
#include <hip/hip_bf16.h>

// MyDeConv1D as GEMM: out[b,t,f] = sum_{j,c} x[b,t+28-4j,c]*W[c,j,f] + cnt(t)*256*bias[f]
// M=32768, N=256, K=2048.
// R6: 4 waves/block (1/SIMD), wave = 128 rows x 64 f via mfma_f32_32x32x16_bf16
//     (4x2 tiles, acc 128 VGPR). Kills the wm-pair B redundancy: B-VMEM 2MB->1MB/CU.
//     8 chunks of 32 ch, 64B LDS rows, slot=(g^r^(r>>2))&3 swizzle, depth-2 rings.

#define B_    16
#define T_    2048
#define C_    256
#define KT    8
#define F_    256
#define SH    28
#define BT    128
#define ROWS  (BT + SH)        // 156
#define CH    32               // channels per chunk
#define CHW   (ROWS * CH)      // 4992 ushorts per buffer (9984 B)

typedef __attribute__((ext_vector_type(8))) short short8;
typedef __attribute__((ext_vector_type(16))) float floatx16;

// Wf frag order: fid = S*8 + w*2 + nf, S = cs*16 + j*2 + kh (cs = 32-ch chunk).
// frag (S,w,nf): lane(l5=l&31,h=l>>5) holds B[k=h*8+i][n=l5]:
//   c = cs*32 + kh*16 + h*8 + i,  f = w*64 + nf*32 + l5.  1KB/frag coalesced.
__global__ __launch_bounds__(256) void wprep_kernel(const float* __restrict__ W,
                                                    ushort* __restrict__ Wf) {
    const int tid  = threadIdx.x;
    const int fid  = blockIdx.x * 4 + (tid >> 6);   // 0..1023
    const int lane = tid & 63;
    const int l5 = lane & 31, h = lane >> 5;
    const int nf = fid & 1, w = (fid >> 1) & 3;
    const int S  = fid >> 3;
    const int kh = S & 1, j = (S >> 1) & 7, cs = S >> 4;
    const int c0 = cs * 32 + kh * 16 + h * 8;
    const int f  = w * 64 + nf * 32 + l5;
    short8 pk;
    #pragma unroll
    for (int i = 0; i < 8; ++i) {
        __hip_bfloat16 v = __float2bfloat16(W[((c0 + i) * KT + j) * F_ + f]);
        pk[i] = *reinterpret_cast<const short*>(&v);
    }
    *reinterpret_cast<short8*>(Wf + (size_t)fid * 512 + lane * 8) = pk;
}

__device__ inline short8 cvt8(float4 a, float4 b) {
    float v[8] = {a.x, a.y, a.z, a.w, b.x, b.y, b.z, b.w};
    short8 r;
    #pragma unroll
    for (int i = 0; i < 8; ++i) {
        __hip_bfloat16 t = __float2bfloat16(v[i]);
        r[i] = *reinterpret_cast<const short*>(&t);
    }
    return r;
}

__global__ __launch_bounds__(256, 1) void deconv_kernel(
        const float* __restrict__ x, const ushort* __restrict__ Wf,
        const float* __restrict__ bias, float* __restrict__ out) {
    __shared__ ushort xs[2 * CHW];                  // 19.5 KiB
    const int t0   = blockIdx.x * BT;
    const int b    = blockIdx.y;
    const int tid  = threadIdx.x;
    const int lane = tid & 63, w = tid >> 6;        // wave owns f [w*64, w*64+64)
    const int l5   = lane & 31, h = lane >> 5;

    // staging: 624 granule tasks (r=task>>2, g=task&3 -> 8 ch), 3 rounds of 256.
    const int r0 = tid >> 2,            g0 = tid & 3;   // rows 0..63
    const int r1 = (tid + 256) >> 2,    g1 = tid & 3;   // rows 64..127
    const int r2 = (tid + 512) >> 2,    g2 = tid & 3;   // rows 128..155 (tid<112)

    float4 A0, B0, A1, B1, A2, B2;

#define STAGE_LOAD(cs_) do {                                                   \
        const float4 z_ = make_float4(0.f, 0.f, 0.f, 0.f);                     \
        A2 = z_; B2 = z_;                                                      \
        {   const float4* p_ = reinterpret_cast<const float4*>(                \
                x + ((size_t)(b * T_ + t0 + r0) * C_ + (cs_) * CH + g0 * 8));  \
            A0 = p_[0]; B0 = p_[1]; }                                          \
        {   const float4* p_ = reinterpret_cast<const float4*>(                \
                x + ((size_t)(b * T_ + t0 + r1) * C_ + (cs_) * CH + g1 * 8));  \
            A1 = p_[0]; B1 = p_[1]; }                                          \
        if (tid < 112 && t0 + r2 < T_) {                                       \
            const float4* p_ = reinterpret_cast<const float4*>(                \
                x + ((size_t)(b * T_ + t0 + r2) * C_ + (cs_) * CH + g2 * 8));  \
            A2 = p_[0]; B2 = p_[1]; } } while (0)

#define STAGE_WRITE(buf_) do {                                                 \
        ushort* d_ = xs + (buf_) * CHW;                                        \
        *reinterpret_cast<short8*>(d_ + r0 * CH +                              \
            (((g0 ^ r0 ^ (r0 >> 2)) & 3) * 8)) = cvt8(A0, B0);                 \
        *reinterpret_cast<short8*>(d_ + r1 * CH +                              \
            (((g1 ^ r1 ^ (r1 >> 2)) & 3) * 8)) = cvt8(A1, B1);                 \
        if (tid < 112)                                                         \
            *reinterpret_cast<short8*>(d_ + r2 * CH +                          \
                (((g2 ^ r2 ^ (r2 >> 2)) & 3) * 8)) = cvt8(A2, B2);             \
        } while (0)

    // A frag (j, kh, mf): lane(l5,h): row = SH-4j + mf*32 + l5,
    // granule g = kh*2+h, slot = (g ^ row ^ (row>>2)) & 3.
#define LOAD_A(buf_, j_, kh_, arr) do {                                        \
        const int rb_ = SH - 4 * (j_) + l5;                                    \
        _Pragma("unroll")                                                      \
        for (int mf = 0; mf < 4; ++mf) {                                       \
            const int row_ = rb_ + mf * 32;                                    \
            const int sl_  = (((kh_) * 2 + h) ^ row_ ^ (row_ >> 2)) & 3;       \
            arr[mf] = *reinterpret_cast<const short8*>(                        \
                xs + (buf_) * CHW + row_ * CH + sl_ * 8);                      \
        } } while (0)

#define LOAD_B(S_, arr) do {                                                   \
        const ushort* p_ = wbase + (size_t)(S_) * 4096;                        \
        arr[0] = *reinterpret_cast<const short8*>(p_);                         \
        arr[1] = *reinterpret_cast<const short8*>(p_ + 512);                   \
        } while (0)

#define DO_MFMA(aa, bb) do {                                                   \
        _Pragma("unroll")                                                      \
        for (int mf = 0; mf < 4; ++mf) {                                       \
            acc[mf][0] = __builtin_amdgcn_mfma_f32_32x32x16_bf16(              \
                aa[mf], bb[0], acc[mf][0], 0, 0, 0);                           \
            acc[mf][1] = __builtin_amdgcn_mfma_f32_32x32x16_bf16(              \
                aa[mf], bb[1], acc[mf][1], 0, 0, 0);                           \
        } } while (0)

    const ushort* wbase = Wf + (size_t)(w * 2) * 512 + lane * 8;

    float bf2[2];
    bf2[0] = bias[w * 64 + l5];
    bf2[1] = bias[w * 64 + 32 + l5];

    floatx16 acc[4][2];
    #pragma unroll
    for (int mf = 0; mf < 4; ++mf)
        #pragma unroll
        for (int nf = 0; nf < 2; ++nf)
            #pragma unroll
            for (int r = 0; r < 16; ++r) acc[mf][nf][r] = 0.f;

    short8 aA[4], aB[4], bA[2], bB[2];

    // prologue
    STAGE_LOAD(0);
    LOAD_B(0, bA);
    LOAD_B(1, bB);
    STAGE_WRITE(0);
    __syncthreads();

    for (int cs = 0; cs < 8; ++cs) {
        const int buf = cs & 1;
        if (cs < 7) STAGE_LOAD(cs + 1);          // next chunk's x loads in flight
        LOAD_A(buf, 0, 0, aA);                   // prime A ring (steps 0,1)
        LOAD_A(buf, 0, 1, aB);
        #pragma unroll
        for (int s = 0; s < 16; s += 2) {
            DO_MFMA(aA, bA);
            if (s < 14) LOAD_A(buf, (s + 2) >> 1, 0, aA);
            LOAD_B((cs * 16 + s + 2) & 127, bA);
            DO_MFMA(aB, bB);
            if (s < 14) LOAD_A(buf, (s + 3) >> 1, 1, aB);
            LOAD_B((cs * 16 + s + 3) & 127, bB);
        }
        if (cs < 7) STAGE_WRITE(buf ^ 1);
        __syncthreads();
    }

    // epilogue: + cnt(t)*256*bias; 32x32 C/D map (m74/m101):
    // col = lane&31, row = (reg&3) + 8*(reg>>2) + 4*(lane>>5)
    #pragma unroll
    for (int mf = 0; mf < 4; ++mf) {
        #pragma unroll
        for (int nf = 0; nf < 2; ++nf) {
            const int f = w * 64 + nf * 32 + l5;
            #pragma unroll
            for (int r = 0; r < 16; ++r) {
                const int rowin = (r & 3) + 8 * (r >> 2) + 4 * h;
                const int t = t0 + mf * 32 + rowin;
                const int jmin = (t < T_ - SH) ? 0 : (((t - (T_ - SH)) >> 2) + 1);
                out[(size_t)(b * T_ + t) * F_ + f] =
                    acc[mf][nf][r] + (float)(8 - jmin) * 256.0f * bf2[nf];
            }
        }
    }
#undef STAGE_LOAD
#undef STAGE_WRITE
#undef LOAD_A
#undef LOAD_B
#undef DO_MFMA
}

extern "C" void kernel_launch(void* const* d_in, const int* in_sizes, int n_in,
                              void* d_out, int out_size, void* d_ws, size_t ws_size,
                              hipStream_t stream) {
    const float* x    = (const float*)d_in[0];
    const float* W    = (const float*)d_in[1];   // (C,KT,F)
    const float* bias = (const float*)d_in[2];
    float* out = (float*)d_out;
    ushort* Wf = (ushort*)d_ws;                  // 1 MiB scratch

    wprep_kernel<<<256, 256, 0, stream>>>(W, Wf);
    dim3 grid(T_ / BT, B_);
    deconv_kernel<<<grid, 256, 0, stream>>>(x, Wf, bias, out);
}

// Round 7
// 45.092 us; speedup vs baseline: 1.3381x; 1.3381x over previous
//
#include <hip/hip_runtime.h>
#include <hip/hip_bf16.h>

// MyDeConv1D as GEMM: out[b,t,f] = sum_{j,c} x[b,t+28-4j,c]*W[c,j,f] + cnt(t)*256*bias[f]
// M=32768, N=256, K=2048, bf16 MFMA 16x16x32.
// R7 = R5 + depth-4 B register ring (B prefetch ~520cy ahead, covers L2 latency).
//     Wave grid W_m=2 x W_f=4 (MF=4,NF=4), LDS [156 rows][128B] slot^=(row&7)
//     swizzle (walked: exact 2-way = free), 4 chunks of 64ch, 1 barrier/chunk.

#define B_    16
#define T_    2048
#define C_    256
#define KT    8
#define F_    256
#define SH    28
#define BT    128
#define ROWS  (BT + SH)        // 156
#define CHW   (ROWS * 64)      // ushorts per chunk buffer (156 rows x 128B)

typedef __attribute__((ext_vector_type(8))) short short8;
typedef __attribute__((ext_vector_type(4))) float floatx4;

// Wf step-major: S = (cs*8 + j)*2 + kh in 0..63, g in 0..15.
// frag (S,g): lane(l16,q) holds B[k=q*8+i][f=g*16+l16], c = cs*64 + kh*32 + q*8 + i.
__global__ __launch_bounds__(256) void wprep_kernel(const float* __restrict__ W,
                                                    ushort* __restrict__ Wf) {
    const int tid  = threadIdx.x;
    const int fid  = blockIdx.x * 4 + (tid >> 6);   // 0..1023
    const int lane = tid & 63;
    const int g    = fid & 15;
    const int S    = fid >> 4;
    const int kh   = S & 1, j = (S >> 1) & 7, cs = S >> 4;
    const int c0   = cs * 64 + kh * 32 + (lane >> 4) * 8;
    const int f    = g * 16 + (lane & 15);
    short8 pk;
    #pragma unroll
    for (int i = 0; i < 8; ++i) {
        __hip_bfloat16 h = __float2bfloat16(W[((c0 + i) * KT + j) * F_ + f]);
        pk[i] = *reinterpret_cast<const short*>(&h);
    }
    *reinterpret_cast<short8*>(Wf + (size_t)fid * 512 + lane * 8) = pk;
}

__device__ inline short8 cvt8(float4 a, float4 b) {
    float v[8] = {a.x, a.y, a.z, a.w, b.x, b.y, b.z, b.w};
    short8 r;
    #pragma unroll
    for (int i = 0; i < 8; ++i) {
        __hip_bfloat16 h = __float2bfloat16(v[i]);
        r[i] = *reinterpret_cast<const short*>(&h);
    }
    return r;
}

__global__ __launch_bounds__(512, 2) void deconv_kernel(
        const float* __restrict__ x, const ushort* __restrict__ Wf,
        const float* __restrict__ bias, float* __restrict__ out) {
    __shared__ ushort xs[2 * CHW];                  // 39 KiB
    const int t0   = blockIdx.x * BT;
    const int b    = blockIdx.y;
    const int tid  = threadIdx.x;
    const int lane = tid & 63, w = tid >> 6;
    const int wf   = w & 3, wm = w >> 2;            // wave = (wm: row-half, wf: f-quarter)
    const int l16  = lane & 15, q = lane >> 4;

    // staging tasks: u -> row=u>>3, 16B slot g=u&7 (8 channels). 3 rounds.
    const int r0 = tid >> 3,          g0 = tid & 7;   // rows 0..63
    const int r1 = (tid + 512) >> 3,  g1 = tid & 7;   // rows 64..127
    const int r2 = (tid + 1024) >> 3, g2 = tid & 7;   // rows 128..155 (tid<224)

    float4 A0, B0, A1, B1, A2, B2;

#define STAGE_LOAD(cs_) do {                                                   \
        const float4 z_ = make_float4(0.f, 0.f, 0.f, 0.f);                     \
        A2 = z_; B2 = z_;                                                      \
        {   const float4* p_ = reinterpret_cast<const float4*>(                \
                x + ((size_t)(b * T_ + t0 + r0) * C_ + (cs_) * 64 + g0 * 8));  \
            A0 = p_[0]; B0 = p_[1]; }                                          \
        {   const float4* p_ = reinterpret_cast<const float4*>(                \
                x + ((size_t)(b * T_ + t0 + r1) * C_ + (cs_) * 64 + g1 * 8));  \
            A1 = p_[0]; B1 = p_[1]; }                                          \
        if (tid < 224 && t0 + r2 < T_) {                                       \
            const float4* p_ = reinterpret_cast<const float4*>(                \
                x + ((size_t)(b * T_ + t0 + r2) * C_ + (cs_) * 64 + g2 * 8));  \
            A2 = p_[0]; B2 = p_[1]; } } while (0)

#define STAGE_WRITE(buf_) do {                                                 \
        ushort* d_ = xs + (buf_) * CHW;                                        \
        *reinterpret_cast<short8*>(d_ + r0 * 64 + ((g0 ^ (r0 & 7)) * 8)) =     \
            cvt8(A0, B0);                                                      \
        *reinterpret_cast<short8*>(d_ + r1 * 64 + ((g1 ^ (r1 & 7)) * 8)) =     \
            cvt8(A1, B1);                                                      \
        if (tid < 224)                                                         \
            *reinterpret_cast<short8*>(d_ + r2 * 64 + ((g2 ^ (r2 & 7)) * 8)) = \
                cvt8(A2, B2);                                                  \
        } while (0)

    // A frag (step s=j*2+kh, frag mf): row = SH-4j + wm*64 + mf*16 + l16,
    // logical slot kh*4+q, physical = logical ^ (row&7).
#define LOAD_A(buf_, s_, arr) do {                                             \
        const int j_ = (s_) >> 1, kh_ = (s_) & 1;                              \
        const int rb_ = SH - 4 * j_ + wm * 64 + l16;                           \
        _Pragma("unroll")                                                      \
        for (int mf = 0; mf < 4; ++mf) {                                       \
            const int row_ = rb_ + mf * 16;                                    \
            arr[mf] = *reinterpret_cast<const short8*>(                        \
                xs + (buf_) * CHW + row_ * 64 +                                \
                (((kh_ * 4 + q) ^ (row_ & 7)) * 8));                           \
        } } while (0)

#define LOAD_B(S_, arr) do {                                                   \
        const ushort* p_ = wbase + (size_t)(S_) * 8192;                        \
        _Pragma("unroll")                                                      \
        for (int nf = 0; nf < 4; ++nf)                                         \
            arr[nf] = *reinterpret_cast<const short8*>(p_ + nf * 512);         \
        } while (0)

#define DO_MFMA(aa, bb) do {                                                   \
        _Pragma("unroll")                                                      \
        for (int mf = 0; mf < 4; ++mf)                                         \
            _Pragma("unroll")                                                  \
            for (int nf = 0; nf < 4; ++nf)                                     \
                acc[mf][nf] = __builtin_amdgcn_mfma_f32_16x16x32_bf16(         \
                    aa[mf], bb[nf], acc[mf][nf], 0, 0, 0);                     \
        } while (0)

    const ushort* wbase = Wf + wf * 2048 + (size_t)lane * 8;

    float bf4[4];
    #pragma unroll
    for (int nf = 0; nf < 4; ++nf) bf4[nf] = bias[wf * 64 + nf * 16 + l16];

    floatx4 acc[4][4];
    #pragma unroll
    for (int mf = 0; mf < 4; ++mf)
        #pragma unroll
        for (int nf = 0; nf < 4; ++nf)
            acc[mf][nf] = (floatx4){0.f, 0.f, 0.f, 0.f};

    short8 aA[4], aB[4];
    short8 br[4][4];                                // depth-4 B ring

    // prologue: stage chunk 0, prime B ring 4 deep
    STAGE_LOAD(0);
    LOAD_B(0, br[0]);
    LOAD_B(1, br[1]);
    LOAD_B(2, br[2]);
    LOAD_B(3, br[3]);
    STAGE_WRITE(0);
    __syncthreads();

    for (int cs = 0; cs < 4; ++cs) {
        const int buf = cs & 1;
        if (cs < 3) STAGE_LOAD(cs + 1);          // next chunk's x loads in flight
        LOAD_A(buf, 0, aA);
        LOAD_A(buf, 1, aB);
        #pragma unroll
        for (int s = 0; s < 16; s += 2) {
            const int S = cs * 16 + s;
            __builtin_amdgcn_s_setprio(1);
            DO_MFMA(aA, br[s & 3]);
            __builtin_amdgcn_s_setprio(0);
            if (s < 14) LOAD_A(buf, s + 2, aA);
            LOAD_B((S + 4) & 63, br[s & 3]);
            __builtin_amdgcn_s_setprio(1);
            DO_MFMA(aB, br[(s + 1) & 3]);
            __builtin_amdgcn_s_setprio(0);
            if (s < 14) LOAD_A(buf, s + 3, aB);
            LOAD_B((S + 5) & 63, br[(s + 1) & 3]);
        }
        if (cs < 3) STAGE_WRITE(buf ^ 1);
        __syncthreads();
    }

    // epilogue: + cnt(t)*256*bias; C/D map col=l16 (f), row=q*4+r
    #pragma unroll
    for (int mf = 0; mf < 4; ++mf) {
        #pragma unroll
        for (int nf = 0; nf < 4; ++nf) {
            const int f = wf * 64 + nf * 16 + l16;
            #pragma unroll
            for (int r = 0; r < 4; ++r) {
                const int t = t0 + wm * 64 + mf * 16 + q * 4 + r;
                const int jmin = (t < T_ - SH) ? 0 : (((t - (T_ - SH)) >> 2) + 1);
                out[(size_t)(b * T_ + t) * F_ + f] =
                    acc[mf][nf][r] + (float)(8 - jmin) * 256.0f * bf4[nf];
            }
        }
    }
#undef STAGE_LOAD
#undef STAGE_WRITE
#undef LOAD_A
#undef LOAD_B
#undef DO_MFMA
}

extern "C" void kernel_launch(void* const* d_in, const int* in_sizes, int n_in,
                              void* d_out, int out_size, void* d_ws, size_t ws_size,
                              hipStream_t stream) {
    const float* x    = (const float*)d_in[0];
    const float* W    = (const float*)d_in[1];   // (C,KT,F)
    const float* bias = (const float*)d_in[2];
    float* out = (float*)d_out;
    ushort* Wf = (ushort*)d_ws;                  // 1 MiB scratch

    wprep_kernel<<<256, 256, 0, stream>>>(W, Wf);
    dim3 grid(T_ / BT, B_);
    deconv_kernel<<<grid, 512, 0, stream>>>(x, Wf, bias, out);
}

// Round 8
// 44.502 us; speedup vs baseline: 1.3559x; 1.0133x over previous
//
#include <hip/hip_runtime.h>
#include <hip/hip_bf16.h>

// MyDeConv1D as GEMM: out[b,t,f] = sum_{j,c} x[b,t+28-4j,c]*W[c,j,f] + cnt(t)*256*bias[f]
// M=32768, N=256, K=2048, bf16 MFMA 16x16x32.
// R8: BT=64, 256-thr blocks (4 waves, wave = 64r x 64f), grid 512 = 2 blocks/CU.
//     Each SIMD hosts waves of 2 INDEPENDENT blocks -> barrier/stage/epilogue of
//     one block overlaps MFMA of the other (m114 mechanism). LDS 23.5 KB/block,
//     slot^=(row&7) swizzle (2-way = free), 4 chunks of 64ch, depth-2 rings.

#define B_    16
#define T_    2048
#define C_    256
#define KT    8
#define F_    256
#define SH    28
#define BT    64
#define ROWS  (BT + SH)        // 92
#define CHW   (ROWS * 64)      // ushorts per chunk buffer (92 rows x 128B)

typedef __attribute__((ext_vector_type(8))) short short8;
typedef __attribute__((ext_vector_type(4))) float floatx4;

// Wf step-major: S = (cs*8 + j)*2 + kh in 0..63, g in 0..15.
// frag (S,g): lane(l16,q) holds B[k=q*8+i][f=g*16+l16], c = cs*64 + kh*32 + q*8 + i.
__global__ __launch_bounds__(256) void wprep_kernel(const float* __restrict__ W,
                                                    ushort* __restrict__ Wf) {
    const int tid  = threadIdx.x;
    const int fid  = blockIdx.x * 4 + (tid >> 6);   // 0..1023
    const int lane = tid & 63;
    const int g    = fid & 15;
    const int S    = fid >> 4;
    const int kh   = S & 1, j = (S >> 1) & 7, cs = S >> 4;
    const int c0   = cs * 64 + kh * 32 + (lane >> 4) * 8;
    const int f    = g * 16 + (lane & 15);
    short8 pk;
    #pragma unroll
    for (int i = 0; i < 8; ++i) {
        __hip_bfloat16 h = __float2bfloat16(W[((c0 + i) * KT + j) * F_ + f]);
        pk[i] = *reinterpret_cast<const short*>(&h);
    }
    *reinterpret_cast<short8*>(Wf + (size_t)fid * 512 + lane * 8) = pk;
}

__device__ inline short8 cvt8(float4 a, float4 b) {
    float v[8] = {a.x, a.y, a.z, a.w, b.x, b.y, b.z, b.w};
    short8 r;
    #pragma unroll
    for (int i = 0; i < 8; ++i) {
        __hip_bfloat16 h = __float2bfloat16(v[i]);
        r[i] = *reinterpret_cast<const short*>(&h);
    }
    return r;
}

__global__ __launch_bounds__(256, 2) void deconv_kernel(
        const float* __restrict__ x, const ushort* __restrict__ Wf,
        const float* __restrict__ bias, float* __restrict__ out) {
    __shared__ ushort xs[2 * CHW];                  // 23.5 KiB
    const int t0   = blockIdx.x * BT;
    const int b    = blockIdx.y;
    const int tid  = threadIdx.x;
    const int lane = tid & 63, wf = tid >> 6;       // 4 waves; wave owns f[wf*64,+64)
    const int l16  = lane & 15, q = lane >> 4;

    // staging tasks: u -> row=u>>3, 16B slot g=u&7 (8 channels). 3 rounds of 256.
    const int r0 = tid >> 3,         g0 = tid & 7;   // rows 0..31  (always valid)
    const int r1 = (tid + 256) >> 3, g1 = tid & 7;   // rows 32..63 (always valid)
    const int r2 = (tid + 512) >> 3, g2 = tid & 7;   // rows 64..91 (tid<224)

    float4 A0, B0, A1, B1, A2, B2;

#define STAGE_LOAD(cs_) do {                                                   \
        const float4 z_ = make_float4(0.f, 0.f, 0.f, 0.f);                     \
        A2 = z_; B2 = z_;                                                      \
        {   const float4* p_ = reinterpret_cast<const float4*>(                \
                x + ((size_t)(b * T_ + t0 + r0) * C_ + (cs_) * 64 + g0 * 8));  \
            A0 = p_[0]; B0 = p_[1]; }                                          \
        {   const float4* p_ = reinterpret_cast<const float4*>(                \
                x + ((size_t)(b * T_ + t0 + r1) * C_ + (cs_) * 64 + g1 * 8));  \
            A1 = p_[0]; B1 = p_[1]; }                                          \
        if (tid < 224 && t0 + r2 < T_) {                                       \
            const float4* p_ = reinterpret_cast<const float4*>(                \
                x + ((size_t)(b * T_ + t0 + r2) * C_ + (cs_) * 64 + g2 * 8));  \
            A2 = p_[0]; B2 = p_[1]; } } while (0)

#define STAGE_WRITE(buf_) do {                                                 \
        ushort* d_ = xs + (buf_) * CHW;                                        \
        *reinterpret_cast<short8*>(d_ + r0 * 64 + ((g0 ^ (r0 & 7)) * 8)) =     \
            cvt8(A0, B0);                                                      \
        *reinterpret_cast<short8*>(d_ + r1 * 64 + ((g1 ^ (r1 & 7)) * 8)) =     \
            cvt8(A1, B1);                                                      \
        if (tid < 224)                                                         \
            *reinterpret_cast<short8*>(d_ + r2 * 64 + ((g2 ^ (r2 & 7)) * 8)) = \
                cvt8(A2, B2);                                                  \
        } while (0)

    // A frag (step s=j*2+kh, frag mf): row = SH-4j + mf*16 + l16 (max 91),
    // logical slot kh*4+q, physical = logical ^ (row&7).
#define LOAD_A(buf_, s_, arr) do {                                             \
        const int j_ = (s_) >> 1, kh_ = (s_) & 1;                              \
        const int rb_ = SH - 4 * j_ + l16;                                     \
        _Pragma("unroll")                                                      \
        for (int mf = 0; mf < 4; ++mf) {                                       \
            const int row_ = rb_ + mf * 16;                                    \
            arr[mf] = *reinterpret_cast<const short8*>(                        \
                xs + (buf_) * CHW + row_ * 64 +                                \
                (((kh_ * 4 + q) ^ (row_ & 7)) * 8));                           \
        } } while (0)

#define LOAD_B(S_, arr) do {                                                   \
        const ushort* p_ = wbase + (size_t)(S_) * 8192;                        \
        _Pragma("unroll")                                                      \
        for (int nf = 0; nf < 4; ++nf)                                         \
            arr[nf] = *reinterpret_cast<const short8*>(p_ + nf * 512);         \
        } while (0)

#define DO_MFMA(aa, bb) do {                                                   \
        _Pragma("unroll")                                                      \
        for (int mf = 0; mf < 4; ++mf)                                         \
            _Pragma("unroll")                                                  \
            for (int nf = 0; nf < 4; ++nf)                                     \
                acc[mf][nf] = __builtin_amdgcn_mfma_f32_16x16x32_bf16(         \
                    aa[mf], bb[nf], acc[mf][nf], 0, 0, 0);                     \
        } while (0)

    const ushort* wbase = Wf + wf * 2048 + (size_t)lane * 8;

    float bf4[4];
    #pragma unroll
    for (int nf = 0; nf < 4; ++nf) bf4[nf] = bias[wf * 64 + nf * 16 + l16];

    floatx4 acc[4][4];
    #pragma unroll
    for (int mf = 0; mf < 4; ++mf)
        #pragma unroll
        for (int nf = 0; nf < 4; ++nf)
            acc[mf][nf] = (floatx4){0.f, 0.f, 0.f, 0.f};

    short8 aA[4], aB[4], bA[4], bB[4];

    // prologue: stage chunk 0, prime B ring
    STAGE_LOAD(0);
    LOAD_B(0, bA);
    LOAD_B(1, bB);
    STAGE_WRITE(0);
    __syncthreads();

    for (int cs = 0; cs < 4; ++cs) {
        const int buf = cs & 1;
        if (cs < 3) STAGE_LOAD(cs + 1);          // next chunk's x loads in flight
        LOAD_A(buf, 0, aA);
        LOAD_A(buf, 1, aB);
        #pragma unroll
        for (int s = 0; s < 16; s += 2) {
            const int S = cs * 16 + s;
            __builtin_amdgcn_s_setprio(1);
            DO_MFMA(aA, bA);
            __builtin_amdgcn_s_setprio(0);
            if (s < 14) LOAD_A(buf, s + 2, aA);
            LOAD_B((S + 2) & 63, bA);
            __builtin_amdgcn_s_setprio(1);
            DO_MFMA(aB, bB);
            __builtin_amdgcn_s_setprio(0);
            if (s < 14) LOAD_A(buf, s + 3, aB);
            LOAD_B((S + 3) & 63, bB);
        }
        if (cs < 3) STAGE_WRITE(buf ^ 1);
        __syncthreads();
    }

    // epilogue: + cnt(t)*256*bias; C/D map col=l16 (f), row=q*4+r
    #pragma unroll
    for (int mf = 0; mf < 4; ++mf) {
        #pragma unroll
        for (int nf = 0; nf < 4; ++nf) {
            const int f = wf * 64 + nf * 16 + l16;
            #pragma unroll
            for (int r = 0; r < 4; ++r) {
                const int t = t0 + mf * 16 + q * 4 + r;
                const int jmin = (t < T_ - SH) ? 0 : (((t - (T_ - SH)) >> 2) + 1);
                out[(size_t)(b * T_ + t) * F_ + f] =
                    acc[mf][nf][r] + (float)(8 - jmin) * 256.0f * bf4[nf];
            }
        }
    }
#undef STAGE_LOAD
#undef STAGE_WRITE
#undef LOAD_A
#undef LOAD_B
#undef DO_MFMA
}

extern "C" void kernel_launch(void* const* d_in, const int* in_sizes, int n_in,
                              void* d_out, int out_size, void* d_ws, size_t ws_size,
                              hipStream_t stream) {
    const float* x    = (const float*)d_in[0];
    const float* W    = (const float*)d_in[1];   // (C,KT,F)
    const float* bias = (const float*)d_in[2];
    float* out = (float*)d_out;
    ushort* Wf = (ushort*)d_ws;                  // 1 MiB scratch

    wprep_kernel<<<256, 256, 0, stream>>>(W, Wf);
    dim3 grid(T_ / BT, B_);
    deconv_kernel<<<grid, 256, 0, stream>>>(x, Wf, bias, out);
}